// Round 1
// baseline (584.070 us; speedup 1.0000x reference)
//
#include <hip/hip_runtime.h>

// Problem: B=16384, D=1024, H=1024
//   g=r*cos(th), phi=r*sin(th), norm=sqrt(max(1-r^2,0))   (1,H)
//   wc1 = x@w1, wc2 = x@w2                                 (B,H)
//   h_t_c1 = g*h_c1 - phi*h_c2 + norm*wc1
//   h_t_c2 = g*h_c2 + phi*h_c1 + norm*wc2
//   h_t = relu(concat(h_t_c1,h_t_c2))                      (B,2H)
// Outputs flat: [h_t_c1 (B*H)] [h_t_c2 (B*H)] [h_t (B*2H)]  fp32
//
// Strategy: single bf16 MFMA GEMM with N=2048 (w1|w2 fused), fused epilogue.

#define Mdim 16384
#define Kdim 1024
#define Hd   1024
#define Ndim 2048

typedef __bf16 bf16x8 __attribute__((ext_vector_type(8)));
typedef float f32x4 __attribute__((ext_vector_type(4)));

__device__ __forceinline__ unsigned short f2bf(float f) {
  union { float f; unsigned int u; } c; c.f = f;
  unsigned int u = c.u;
  u += 0x7fffu + ((u >> 16) & 1u);   // round-to-nearest-even
  return (unsigned short)(u >> 16);
}

__device__ __forceinline__ void gload16(const unsigned short* g, unsigned short* l) {
  __builtin_amdgcn_global_load_lds(
      (const __attribute__((address_space(1))) void*)g,
      (__attribute__((address_space(3))) void*)l,
      16, 0, 0);
}

// ---- pre-kernel 1: x fp32 -> bf16 (row-major [M][K] unchanged) ----
__global__ __launch_bounds__(256) void convert_x_kernel(const float* __restrict__ x,
                                                        unsigned short* __restrict__ xb) {
  const long n4 = (long)Mdim * Kdim / 4;
  long i = (long)blockIdx.x * blockDim.x + threadIdx.x;
  const long stride = (long)gridDim.x * blockDim.x;
  for (; i < n4; i += stride) {
    float4 v = ((const float4*)x)[i];
    ushort4 o;
    o.x = f2bf(v.x); o.y = f2bf(v.y); o.z = f2bf(v.z); o.w = f2bf(v.w);
    ((ushort4*)xb)[i] = o;
  }
}

// ---- pre-kernel 2: wT[n][k] = w{1,2}[k][n] as bf16, n in [0,2048) ----
__global__ __launch_bounds__(256) void transpose_w_kernel(const float* __restrict__ w1,
                                                          const float* __restrict__ w2,
                                                          unsigned short* __restrict__ wT) {
  __shared__ unsigned short tile[32][33];
  const int b = blockIdx.x;          // 2048 blocks: 32 k-tiles x 64 n-tiles
  const int ktile = b & 31;
  const int ntile = b >> 5;
  const int k0 = ktile * 32, n0 = ntile * 32;
  const float* src = (n0 < Hd) ? w1 : w2;
  const int nc0 = (n0 < Hd) ? n0 : (n0 - Hd);
  const int r = threadIdx.x >> 5;    // 0..7
  const int c = threadIdx.x & 31;
#pragma unroll
  for (int i = 0; i < 32; i += 8)
    tile[r + i][c] = f2bf(src[(long)(k0 + r + i) * Hd + nc0 + c]);
  __syncthreads();
#pragma unroll
  for (int i = 0; i < 32; i += 8)
    wT[(long)(n0 + r + i) * Kdim + k0 + c] = tile[c][r + i];
}

// ---- pre-kernel 3: g, phi, norm ----
__global__ __launch_bounds__(256) void gpn_kernel(const float* __restrict__ r,
                                                  const float* __restrict__ th,
                                                  float* __restrict__ gpn) {
  const int h = blockIdx.x * blockDim.x + threadIdx.x;
  if (h < Hd) {
    float rv = r[h], tv = th[h];
    gpn[h]          = rv * cosf(tv);
    gpn[Hd + h]     = rv * sinf(tv);
    gpn[2 * Hd + h] = sqrtf(fmaxf(1.0f - rv * rv, 0.0f));
  }
}

// ---- main: 128x128 tile bf16 MFMA GEMM (M=16384, N=2048, K=1024), fused epilogue ----
__global__ __launch_bounds__(256) void gemm_fused_kernel(
    const unsigned short* __restrict__ xb,   // [M][K] bf16
    const unsigned short* __restrict__ wT,   // [N][K] bf16
    const float* __restrict__ gpn,           // [3][H]
    const float* __restrict__ hc1,           // [M][H]
    const float* __restrict__ hc2,           // [M][H]
    float* __restrict__ out) {               // [M*H | M*H | M*2H]
  __shared__ unsigned short As[128 * 32];
  __shared__ unsigned short Bs[128 * 32];

  // XCD-aware swizzle: 2048 blocks, 8 XCDs -> contiguous 256-tile chunk per XCD
  const int bid = blockIdx.x;
  const int tile = (bid & 7) * 256 + (bid >> 3);
  const int tn = tile & 15;          // 16 N-tiles
  const int tm = tile >> 4;          // 128 M-tiles
  const int m0 = tm * 128, n0 = tn * 128;

  const int t = threadIdx.x;
  const int w = t >> 6;              // wave 0..3
  const int l = t & 63;
  const int wr = w >> 1, wc = w & 1; // 2x2 waves, each 64x64
  const int lr = l & 15;
  const int lk = (l >> 4) * 8;

  // staging addresses: chunk c = i*256+t covers row c/4, k-offset (c%4)*8
  const unsigned short* ga0 = xb + (long)(m0 + (t >> 2)) * Kdim + (t & 3) * 8;
  const unsigned short* ga1 = ga0 + (long)64 * Kdim;
  const unsigned short* gb0 = wT + (long)(n0 + (t >> 2)) * Kdim + (t & 3) * 8;
  const unsigned short* gb1 = gb0 + (long)64 * Kdim;
  unsigned short* la0 = &As[t * 8];
  unsigned short* la1 = &As[2048 + t * 8];
  unsigned short* lb0 = &Bs[t * 8];
  unsigned short* lb1 = &Bs[2048 + t * 8];

  f32x4 acc[4][4] = {};

  for (int kk = 0; kk < Kdim; kk += 32) {
    gload16(ga0 + kk, la0);
    gload16(ga1 + kk, la1);
    gload16(gb0 + kk, lb0);
    gload16(gb1 + kk, lb1);
    __syncthreads();   // compiler drains vmcnt before barrier

    bf16x8 a[4], b[4];
#pragma unroll
    for (int mi = 0; mi < 4; ++mi)
      a[mi] = *(const bf16x8*)&As[(wr * 64 + mi * 16 + lr) * 32 + lk];
#pragma unroll
    for (int ni = 0; ni < 4; ++ni)
      b[ni] = *(const bf16x8*)&Bs[(wc * 64 + ni * 16 + lr) * 32 + lk];
#pragma unroll
    for (int mi = 0; mi < 4; ++mi)
#pragma unroll
      for (int ni = 0; ni < 4; ++ni)
        acc[mi][ni] = __builtin_amdgcn_mfma_f32_16x16x32_bf16(a[mi], b[ni], acc[mi][ni], 0, 0, 0);
    __syncthreads();   // protect LDS before next stage
  }

  // epilogue: C/D layout col=lane&15, row=(lane>>4)*4+reg
  const int cr = (l >> 4) * 4;
  const int cc = l & 15;
  const bool second = (n0 >= Hd);
  float* outc = second ? (out + (long)Mdim * Hd) : out;
  float* out2 = out + 2L * Mdim * Hd;
  const int o2 = second ? Hd : 0;

#pragma unroll
  for (int ni = 0; ni < 4; ++ni) {
    const int col = n0 + wc * 64 + ni * 16 + cc;
    const int h = col & (Hd - 1);
    const float gg = gpn[h];
    const float pp = gpn[Hd + h];
    const float nm = gpn[2 * Hd + h];
#pragma unroll
    for (int mi = 0; mi < 4; ++mi) {
#pragma unroll
      for (int j = 0; j < 4; ++j) {
        const long row = m0 + wr * 64 + mi * 16 + cr + j;
        const float h1 = hc1[row * Hd + h];
        const float h2 = hc2[row * Hd + h];
        const float wx = acc[mi][ni][j] * nm;
        const float v = second ? fmaf(gg, h2, fmaf(pp, h1, wx))
                               : fmaf(gg, h1, fmaf(-pp, h2, wx));
        outc[row * Hd + h] = v;
        out2[row * (long)Ndim + o2 + h] = fmaxf(v, 0.0f);
      }
    }
  }
}

extern "C" void kernel_launch(void* const* d_in, const int* in_sizes, int n_in,
                              void* d_out, int out_size, void* d_ws, size_t ws_size,
                              hipStream_t stream) {
  const float* hc1 = (const float*)d_in[0];
  const float* hc2 = (const float*)d_in[1];
  const float* x   = (const float*)d_in[2];
  const float* rp  = (const float*)d_in[3];
  const float* th  = (const float*)d_in[4];
  const float* w1  = (const float*)d_in[5];
  const float* w2  = (const float*)d_in[6];
  float* out = (float*)d_out;

  char* ws = (char*)d_ws;
  unsigned short* xb = (unsigned short*)ws;                               // 32 MB
  unsigned short* wT = (unsigned short*)(ws + (size_t)Mdim * Kdim * 2);   // 4 MB
  float* gpn = (float*)(ws + (size_t)Mdim * Kdim * 2 + (size_t)Ndim * Kdim * 2);

  convert_x_kernel<<<2048, 256, 0, stream>>>(x, xb);
  transpose_w_kernel<<<2048, 256, 0, stream>>>(w1, w2, wT);
  gpn_kernel<<<4, 256, 0, stream>>>(rp, th, gpn);
  gemm_fused_kernel<<<2048, 256, 0, stream>>>(xb, wT, gpn, hc1, hc2, out);
}

// Round 7
// 505.654 us; speedup vs baseline: 1.1551x; 1.1551x over previous
//
#include <hip/hip_runtime.h>

// B=16384, D=1024, H=1024
//   g=r*cos(th), phi=r*sin(th), norm=sqrt(max(1-r^2,0))
//   h_t_c1 = g*h_c1 - phi*h_c2 + norm*(x@w1)
//   h_t_c2 = g*h_c2 + phi*h_c1 + norm*(x@w2)
//   h_t = relu(concat(h_t_c1,h_t_c2))
// Outputs flat fp32: [h_t_c1 (B*H)] [h_t_c2 (B*H)] [h_t (B*2H)]
//
// GEMM: 256x256 tile, BK=64, 8 waves (2x4), double-buffered LDS (128 KiB),
// counted vmcnt(8) (never drains in main loop), T2 XOR swizzle, T5 setprio,
// T1 XCD-aware block swizzle. norm pre-folded into bf16 weights.
// wT row layout interleaves w1/w2 halves per 128-h block so each GEMM block
// covers one h-range for BOTH output halves (hc1/hc2 read once from HBM).

#define Mdim 16384
#define Kdim 1024
#define Hd   1024
#define MH   16777216   // Mdim*Hd

typedef __bf16 bf16x8 __attribute__((ext_vector_type(8)));
typedef float f32x4 __attribute__((ext_vector_type(4)));

__device__ __forceinline__ unsigned short f2bf(float f) {
  union { float f; unsigned int u; } c; c.f = f;
  unsigned int u = c.u;
  u += 0x7fffu + ((u >> 16) & 1u);   // RNE
  return (unsigned short)(u >> 16);
}

__device__ __forceinline__ void gload16(const void* g, void* l) {
  __builtin_amdgcn_global_load_lds(
      (const __attribute__((address_space(1))) void*)g,
      (__attribute__((address_space(3))) void*)l,
      16, 0, 0);
}

// ---- pre-kernel 1: x fp32 -> bf16, plus g/phi table (fused) ----
__global__ __launch_bounds__(256) void convert_gpn_kernel(
    const float* __restrict__ x, unsigned short* __restrict__ xb,
    const float* __restrict__ rp, const float* __restrict__ th,
    float* __restrict__ gphi) {
  const int b = blockIdx.x;
  if (b < 2048) {
    const long n4 = (long)Mdim * Kdim / 4;
    long i = (long)b * 256 + threadIdx.x;
    for (; i < n4; i += 2048L * 256) {
      float4 v = ((const float4*)x)[i];
      ushort4 o;
      o.x = f2bf(v.x); o.y = f2bf(v.y); o.z = f2bf(v.z); o.w = f2bf(v.w);
      ((ushort4*)xb)[i] = o;
    }
  } else {
    const int h = (b - 2048) * 256 + threadIdx.x;
    if (h < Hd) {
      float rv = rp[h], tv = th[h];
      gphi[h]      = rv * cosf(tv);
      gphi[Hd + h] = rv * sinf(tv);
    }
  }
}

// ---- pre-kernel 2: wT[n][k] = norm[h] * w{1,2}[k][h] (bf16), interleaved:
//      n = (h>>7)*256 + half*128 + (h&127) ----
__global__ __launch_bounds__(256) void transpose_w_kernel(
    const float* __restrict__ w1, const float* __restrict__ w2,
    const float* __restrict__ rp, unsigned short* __restrict__ wT) {
  __shared__ unsigned short tile[32][33];
  const int b = blockIdx.x;             // 32 k-tiles x 64 col-tiles
  const int kt = b & 31, ct = b >> 5;
  const int half = ct & 1, h0 = (ct >> 1) * 32;
  const int k0 = kt * 32;
  const int n0 = (h0 >> 7) * 256 + half * 128 + (h0 & 127);
  const float* src = half ? w2 : w1;
  const int r = threadIdx.x >> 5, c = threadIdx.x & 31;
  const float rv = rp[h0 + c];
  const float nm = sqrtf(fmaxf(1.0f - rv * rv, 0.0f));
#pragma unroll
  for (int i = 0; i < 32; i += 8)
    tile[r + i][c] = f2bf(src[(long)(k0 + r + i) * Hd + h0 + c] * nm);
  __syncthreads();
#pragma unroll
  for (int i = 0; i < 32; i += 8)
    wT[(long)(n0 + r + i) * Kdim + k0 + c] = tile[c][r + i];
}

#define QUADM(MQ, NQ)                                                          \
  __builtin_amdgcn_s_setprio(1);                                               \
  _Pragma("unroll")                                                            \
  for (int ks = 0; ks < 2; ++ks) {                                             \
    _Pragma("unroll")                                                          \
    for (int mi = 0; mi < 4; ++mi) {                                           \
      _Pragma("unroll")                                                        \
      for (int ni = 0; ni < 2; ++ni) {                                         \
        acc[(MQ)*4 + mi][(NQ)*2 + ni] =                                        \
            __builtin_amdgcn_mfma_f32_16x16x32_bf16(                           \
                a[mi][ks], bb[(NQ)*2 + ni][ks],                                \
                acc[(MQ)*4 + mi][(NQ)*2 + ni], 0, 0, 0);                       \
      }                                                                        \
    }                                                                          \
  }                                                                            \
  __builtin_amdgcn_s_setprio(0);

#define READ_A(MQ)                                                             \
  _Pragma("unroll")                                                            \
  for (int mi = 0; mi < 4; ++mi) {                                             \
    _Pragma("unroll")                                                          \
    for (int ks = 0; ks < 2; ++ks) {                                           \
      a[mi][ks] = *(const bf16x8*)(Ab + (wm*128 + (MQ)*64 + mi*16 + lr)*128 +  \
                                   ((ks*64 + kq*16) ^ swzl));                  \
    }                                                                          \
  }

// ---- main GEMM: M=16384, N=2048(K-major wT), K=1024; 512 blocks x 512 thr ----
__global__ __launch_bounds__(512, 2) void gemm256_kernel(
    const unsigned short* __restrict__ xb,   // [M][K] bf16
    const unsigned short* __restrict__ wT,   // [N][K] bf16 (norm-scaled, interleaved)
    const float* __restrict__ gphi,          // [2][H]
    const float* __restrict__ hc1,           // [M][H]
    const float* __restrict__ hc2,           // [M][H]
    float* __restrict__ out) {
  extern __shared__ char smem[];             // 131072 B: 2 bufs x (A 32K | B 32K)

  const int tid = threadIdx.x;
  const int lane = tid & 63;
  const int wv = tid >> 6;                   // 0..7
  const int wm = wv >> 2, wn = wv & 3;       // 2 x 4 waves
  const int lr = lane & 15, kq = lane >> 4;  // frag row / k-quarter
  const int swzl = (lr & 7) << 4;            // T2 read-side swizzle

  // T1: XCD-aware swizzle, 512 blocks -> 64-tile contiguous chunk per XCD
  const int g = (blockIdx.x & 7) * 64 + (blockIdx.x >> 3);
  const int tm = g >> 3, tn = g & 7;
  const int m0 = tm * 256, n0 = tn * 256;

  const char* xbB = (const char*)xb;
  const char* wTB = (const char*)wT;
  const int rA = tid >> 3;                                  // 0..63
  const int swsrc = (((tid & 7) ^ ((tid >> 3) & 7)) << 4);  // pre-swizzled source

  auto stage = [&](int buf, int kt) {
    const char* as = xbB + ((size_t)(m0 + rA) << 11) + kt * 128 + swsrc;
    const char* bs = wTB + ((size_t)(n0 + rA) << 11) + kt * 128 + swsrc;
    char* ld = smem + buf * 65536 + tid * 16;
#pragma unroll
    for (int i = 0; i < 4; ++i) gload16(as + (size_t)i * 131072, ld + i * 8192);
#pragma unroll
    for (int i = 0; i < 4; ++i) gload16(bs + (size_t)i * 131072, ld + 32768 + i * 8192);
  };

  stage(0, 0);
  stage(1, 1);
  asm volatile("s_waitcnt vmcnt(8)" ::: "memory");   // tile0 landed, tile1 in flight
  __builtin_amdgcn_s_barrier();

  f32x4 acc[8][4] = {};
  bf16x8 a[4][2], bb[4][2];

  for (int t = 0; t < 16; ++t) {
    const char* Ab = smem + (t & 1) * 65536;
    const char* Bb = Ab + 32768;

    READ_A(0)
#pragma unroll
    for (int ni = 0; ni < 4; ++ni) {
#pragma unroll
      for (int ks = 0; ks < 2; ++ks) {
        bb[ni][ks] = *(const bf16x8*)(Bb + (wn*64 + ni*16 + lr)*128 +
                                      ((ks*64 + kq*16) ^ swzl));
      }
    }
    __builtin_amdgcn_s_barrier();

    QUADM(0, 0)
    __builtin_amdgcn_s_barrier();
    QUADM(0, 1)
    __builtin_amdgcn_s_barrier();

    READ_A(1)
    asm volatile("s_waitcnt lgkmcnt(0)" ::: "memory");   // my reads of this buf done
    __builtin_amdgcn_sched_barrier(0);
    __builtin_amdgcn_s_barrier();                        // ALL waves done reading buf
    __builtin_amdgcn_sched_barrier(0);

    stage(t & 1, (t + 2 < 16) ? t + 2 : 15);             // safe: buf fully consumed

    QUADM(1, 0)
    __builtin_amdgcn_s_barrier();
    QUADM(1, 1)
    asm volatile("s_waitcnt vmcnt(8)" ::: "memory");     // next tile landed; keep 8 in flight
    __builtin_amdgcn_sched_barrier(0);
    __builtin_amdgcn_s_barrier();
    __builtin_amdgcn_sched_barrier(0);
  }
  asm volatile("s_waitcnt vmcnt(0)" ::: "memory");       // drain dummy stages before exit

  // ---- fused epilogue ----
  const int crow = (lane >> 4) * 4;
  const int halfsel = wn >> 1;                 // 0: c1-half, 1: c2-half
  float* outc = out + (size_t)halfsel * MH;
  float* o2b  = out + 2 * (size_t)MH;

  float gg[4], pp[4];
  int hx[4];
#pragma unroll
  for (int ni = 0; ni < 4; ++ni) {
    const int hl = (wn & 1) * 64 + ni * 16 + lr;
    const int h = tn * 128 + hl;
    hx[ni] = h;
    gg[ni] = gphi[h];
    pp[ni] = gphi[Hd + h];
  }

#pragma unroll
  for (int mi = 0; mi < 8; ++mi) {
#pragma unroll
    for (int j = 0; j < 4; ++j) {
      const size_t row = (size_t)m0 + wm * 128 + mi * 16 + crow + j;
      const float* p1 = hc1 + row * Hd;
      const float* p2 = hc2 + row * Hd;
      float* oc = outc + row * Hd;
      float* o2 = o2b + row * 2048 + (size_t)halfsel * Hd;
#pragma unroll
      for (int ni = 0; ni < 4; ++ni) {
        const int h = hx[ni];
        const float h1 = p1[h];
        const float h2 = p2[h];
        const float wx = acc[mi][ni][j];     // norm already folded into wT
        const float v = halfsel ? fmaf(gg[ni], h2, fmaf(pp[ni], h1, wx))
                                : fmaf(gg[ni], h1, fmaf(-pp[ni], h2, wx));
        oc[h] = v;
        o2[h] = fmaxf(v, 0.0f);
      }
    }
  }
}

extern "C" void kernel_launch(void* const* d_in, const int* in_sizes, int n_in,
                              void* d_out, int out_size, void* d_ws, size_t ws_size,
                              hipStream_t stream) {
  const float* hc1 = (const float*)d_in[0];
  const float* hc2 = (const float*)d_in[1];
  const float* x   = (const float*)d_in[2];
  const float* rp  = (const float*)d_in[3];
  const float* th  = (const float*)d_in[4];
  const float* w1  = (const float*)d_in[5];
  const float* w2  = (const float*)d_in[6];
  float* out = (float*)d_out;

  char* ws = (char*)d_ws;
  unsigned short* xb = (unsigned short*)ws;                                   // 32 MB
  unsigned short* wT = (unsigned short*)(ws + (size_t)Mdim * Kdim * 2);       // 4 MB
  float* gphi = (float*)(ws + (size_t)Mdim * Kdim * 2 + (size_t)2048 * Kdim * 2);

  (void)hipFuncSetAttribute((const void*)gemm256_kernel,
                            hipFuncAttributeMaxDynamicSharedMemorySize, 131072);

  convert_gpn_kernel<<<2052, 256, 0, stream>>>(x, xb, rp, th, gphi);
  transpose_w_kernel<<<2048, 256, 0, stream>>>(w1, w2, rp, wT);
  gemm256_kernel<<<512, 512, 131072, stream>>>(xb, wT, gphi, hc1, hc2, out);
}

// Round 8
// 504.530 us; speedup vs baseline: 1.1577x; 1.0022x over previous
//
#include <hip/hip_runtime.h>

// B=16384, D=1024, H=1024
//   g=r*cos(th), phi=r*sin(th), norm=sqrt(max(1-r^2,0))
//   h_t_c1 = g*h_c1 - phi*h_c2 + norm*(x@w1)
//   h_t_c2 = g*h_c2 + phi*h_c1 + norm*(x@w2)
//   h_t = relu(concat(h_t_c1,h_t_c2))
// Outputs flat fp32: [h_t_c1 (B*H)] [h_t_c2 (B*H)] [h_t (B*2H)]
//
// R8: 128x128 tile (A 128xK, B = c1/c2 strips of same 64-h range), BK=64,
// 4 waves, 2-buffer 64 KiB LDS -> 2 blocks/CU. 2 barriers/iter, one 32-MFMA
// cluster, counted vmcnt(8). Zero-conflict XOR swizzle kept (128-B rows).

#define Mdim 16384
#define Kdim 1024
#define Hd   1024
#define MH   16777216   // Mdim*Hd

typedef __bf16 bf16x8 __attribute__((ext_vector_type(8)));
typedef float f32x4 __attribute__((ext_vector_type(4)));

__device__ __forceinline__ unsigned short f2bf(float f) {
  union { float f; unsigned int u; } c; c.f = f;
  unsigned int u = c.u;
  u += 0x7fffu + ((u >> 16) & 1u);   // RNE
  return (unsigned short)(u >> 16);
}

__device__ __forceinline__ void gload16(const void* g, void* l) {
  __builtin_amdgcn_global_load_lds(
      (const __attribute__((address_space(1))) void*)g,
      (__attribute__((address_space(3))) void*)l,
      16, 0, 0);
}

// ---- pre-kernel 1: x fp32 -> bf16, plus g/phi table (fused) ----
__global__ __launch_bounds__(256) void convert_gpn_kernel(
    const float* __restrict__ x, unsigned short* __restrict__ xb,
    const float* __restrict__ rp, const float* __restrict__ th,
    float* __restrict__ gphi) {
  const int b = blockIdx.x;
  if (b < 2048) {
    const long n4 = (long)Mdim * Kdim / 4;
    long i = (long)b * 256 + threadIdx.x;
    for (; i < n4; i += 2048L * 256) {
      float4 v = ((const float4*)x)[i];
      ushort4 o;
      o.x = f2bf(v.x); o.y = f2bf(v.y); o.z = f2bf(v.z); o.w = f2bf(v.w);
      ((ushort4*)xb)[i] = o;
    }
  } else {
    const int h = (b - 2048) * 256 + threadIdx.x;
    if (h < Hd) {
      float rv = rp[h], tv = th[h];
      gphi[h]      = rv * cosf(tv);
      gphi[Hd + h] = rv * sinf(tv);
    }
  }
}

// ---- pre-kernel 2: wT[n][k] = norm[h] * w{1,2}[k][h] (bf16), interleaved:
//      n = (h>>7)*256 + half*128 + (h&127) ----
__global__ __launch_bounds__(256) void transpose_w_kernel(
    const float* __restrict__ w1, const float* __restrict__ w2,
    const float* __restrict__ rp, unsigned short* __restrict__ wT) {
  __shared__ unsigned short tile[32][33];
  const int b = blockIdx.x;             // 32 k-tiles x 64 col-tiles
  const int kt = b & 31, ct = b >> 5;
  const int half = ct & 1, h0 = (ct >> 1) * 32;
  const int k0 = kt * 32;
  const int n0 = (h0 >> 7) * 256 + half * 128 + (h0 & 127);
  const float* src = half ? w2 : w1;
  const int r = threadIdx.x >> 5, c = threadIdx.x & 31;
  const float rv = rp[h0 + c];
  const float nm = sqrtf(fmaxf(1.0f - rv * rv, 0.0f));
#pragma unroll
  for (int i = 0; i < 32; i += 8)
    tile[r + i][c] = f2bf(src[(long)(k0 + r + i) * Hd + h0 + c] * nm);
  __syncthreads();
#pragma unroll
  for (int i = 0; i < 32; i += 8)
    wT[(long)(n0 + r + i) * Kdim + k0 + c] = tile[c][r + i];
}

// ---- main GEMM: 2048 blocks x 256 thr; block = 128 m-rows x 64 h x 2 halves --
__global__ __launch_bounds__(256, 2) void gemm128_kernel(
    const unsigned short* __restrict__ xb,   // [M][K] bf16
    const unsigned short* __restrict__ wT,   // [N][K] bf16 (norm-scaled, interleaved)
    const float* __restrict__ gphi,          // [2][H]
    const float* __restrict__ hc1,           // [M][H]
    const float* __restrict__ hc2,           // [M][H]
    float* __restrict__ out) {
  extern __shared__ char smem[];             // 65536 B: 2 bufs x (A 16K | B 16K)

  const int tid = threadIdx.x;
  const int lane = tid & 63;
  const int wv = tid >> 6;                   // 0..3
  const int wm = wv >> 1, wn = wv & 1;       // 2x2 waves; wn = output half
  const int lr = lane & 15, kq = lane >> 4;
  const int swzl = (lr & 7) << 4;            // read-side XOR swizzle (bits 4-6)

  // T1: XCD swizzle, 2048 blocks -> 256-contiguous g per XCD
  const int g = (blockIdx.x & 7) * 256 + (blockIdx.x >> 3);
  const int tm = g >> 4, hb = g & 15;        // 128 m-tiles x 16 h-tiles
  const int m0 = tm * 128;
  const int nbase = (hb >> 1) * 256 + (hb & 1) * 64;  // wT n for strip row rB:
                                                       // nbase + (rB>>6)*128 + (rB&63)
  const char* xbB = (const char*)xb;
  const char* wTB = (const char*)wT;
  const int r0 = tid >> 3;                                  // 0..31, +32 per instr
  const int swsrc = (((tid & 7) ^ ((tid >> 3) & 7)) << 4);  // pre-swizzled source

  auto stage = [&](int buf, int kt) {
    char* ldA = smem + buf * 32768 + tid * 16;
    char* ldB = ldA + 16384;
#pragma unroll
    for (int i = 0; i < 4; ++i) {
      const int r = r0 + 32 * i;             // r&7 invariant across i
      gload16(xbB + ((size_t)(m0 + r) << 11) + kt * 128 + swsrc, ldA + i * 4096);
      const int n = nbase + ((r >> 6) << 7) + (r & 63);
      gload16(wTB + ((size_t)n << 11) + kt * 128 + swsrc, ldB + i * 4096);
    }
  };

  stage(0, 0);
  stage(1, 1);
  asm volatile("s_waitcnt vmcnt(8)" ::: "memory");   // tile0 landed, tile1 in flight
  __builtin_amdgcn_s_barrier();

  f32x4 acc[4][4] = {};
  bf16x8 a[4][2], bb[4][2];

  for (int t = 0; t < 16; ++t) {
    const char* Ab = smem + (t & 1) * 32768;
    const char* Bb = Ab + 16384;

#pragma unroll
    for (int mi = 0; mi < 4; ++mi)
#pragma unroll
      for (int ks = 0; ks < 2; ++ks)
        a[mi][ks] = *(const bf16x8*)(Ab + (wm * 64 + mi * 16 + lr) * 128 +
                                     ((ks * 64 + kq * 16) ^ swzl));
#pragma unroll
    for (int ni = 0; ni < 4; ++ni)
#pragma unroll
      for (int ks = 0; ks < 2; ++ks)
        bb[ni][ks] = *(const bf16x8*)(Bb + (wn * 64 + ni * 16 + lr) * 128 +
                                      ((ks * 64 + kq * 16) ^ swzl));

    asm volatile("s_waitcnt lgkmcnt(0)" ::: "memory");   // my reads of this buf done
    __builtin_amdgcn_sched_barrier(0);
    __builtin_amdgcn_s_barrier();                        // ALL waves done reading buf
    __builtin_amdgcn_sched_barrier(0);

    stage(t & 1, (t + 2 < 16) ? t + 2 : 15);             // overwrite fully-read buf

    __builtin_amdgcn_s_setprio(1);
#pragma unroll
    for (int ks = 0; ks < 2; ++ks)
#pragma unroll
      for (int mi = 0; mi < 4; ++mi)
#pragma unroll
        for (int ni = 0; ni < 4; ++ni)
          acc[mi][ni] = __builtin_amdgcn_mfma_f32_16x16x32_bf16(
              a[mi][ks], bb[ni][ks], acc[mi][ni], 0, 0, 0);
    __builtin_amdgcn_s_setprio(0);

    asm volatile("s_waitcnt vmcnt(8)" ::: "memory");     // next tile landed; 8 in flight
    __builtin_amdgcn_sched_barrier(0);
    __builtin_amdgcn_s_barrier();
    __builtin_amdgcn_sched_barrier(0);
  }
  asm volatile("s_waitcnt vmcnt(0)" ::: "memory");       // drain dup stages before exit

  // ---- fused epilogue: halfsel = wn; h-range = hb*64 .. +64 ----
  const int crow = kq * 4;
  const int halfsel = wn;
  float* outc = out + (size_t)halfsel * MH;
  float* o2b  = out + 2 * (size_t)MH + (size_t)halfsel * Hd;

  float gg[4], pp[4];
  int hx[4];
#pragma unroll
  for (int ni = 0; ni < 4; ++ni) {
    const int h = hb * 64 + ni * 16 + lr;
    hx[ni] = h;
    gg[ni] = gphi[h];
    pp[ni] = gphi[Hd + h];
  }

#pragma unroll
  for (int mi = 0; mi < 4; ++mi) {
#pragma unroll
    for (int j = 0; j < 4; ++j) {
      const size_t row = (size_t)m0 + wm * 64 + mi * 16 + crow + j;
      const float* p1 = hc1 + row * Hd;
      const float* p2 = hc2 + row * Hd;
      float* oc = outc + row * Hd;
      float* o2 = o2b + row * 2048;
#pragma unroll
      for (int ni = 0; ni < 4; ++ni) {
        const int h = hx[ni];
        const float h1 = p1[h];
        const float h2 = p2[h];
        const float wx = acc[mi][ni][j];     // norm folded into wT
        const float v = halfsel ? fmaf(gg[ni], h2, fmaf(pp[ni], h1, wx))
                                : fmaf(gg[ni], h1, fmaf(-pp[ni], h2, wx));
        oc[h] = v;
        o2[h] = fmaxf(v, 0.0f);
      }
    }
  }
}

extern "C" void kernel_launch(void* const* d_in, const int* in_sizes, int n_in,
                              void* d_out, int out_size, void* d_ws, size_t ws_size,
                              hipStream_t stream) {
  const float* hc1 = (const float*)d_in[0];
  const float* hc2 = (const float*)d_in[1];
  const float* x   = (const float*)d_in[2];
  const float* rp  = (const float*)d_in[3];
  const float* th  = (const float*)d_in[4];
  const float* w1  = (const float*)d_in[5];
  const float* w2  = (const float*)d_in[6];
  float* out = (float*)d_out;

  char* ws = (char*)d_ws;
  unsigned short* xb = (unsigned short*)ws;                                   // 32 MB
  unsigned short* wT = (unsigned short*)(ws + (size_t)Mdim * Kdim * 2);       // 4 MB
  float* gphi = (float*)(ws + (size_t)Mdim * Kdim * 2 + (size_t)2048 * Kdim * 2);

  (void)hipFuncSetAttribute((const void*)gemm128_kernel,
                            hipFuncAttributeMaxDynamicSharedMemorySize, 65536);

  convert_gpn_kernel<<<2052, 256, 0, stream>>>(x, xb, rp, th, gphi);
  transpose_w_kernel<<<2048, 256, 0, stream>>>(w1, w2, rp, wT);
  gemm128_kernel<<<2048, 256, 65536, stream>>>(xb, wT, gphi, hc1, hc2, out);
}